// Round 1
// baseline (254.222 us; speedup 1.0000x reference)
//
#include <hip/hip_runtime.h>

// Bilinear backward warp: img [B,C,H,W] f32, flo [B,2,H,W] f32 -> out [B,C,H,W] f32
// B=8, C=64, H=256, W=448

#define BN 8
#define CN 64
#define HN 256
#define WN 448
#define HW (HN * WN)

__global__ __launch_bounds__(256) void warp_kernel(const float* __restrict__ img,
                                                   const float* __restrict__ flo,
                                                   float* __restrict__ out) {
    int pix = blockIdx.x * blockDim.x + threadIdx.x;  // over B*H*W
    if (pix >= BN * HW) return;
    int b = pix / HW;
    int hw = pix - b * HW;
    int h = hw / WN;
    int w = hw - h * WN;

    // flow: [B, 2, H, W]
    const float fx = flo[(size_t)b * 2 * HW + hw];
    const float fy = flo[(size_t)b * 2 * HW + HW + hw];
    const float x = (float)w + fx;
    const float y = (float)h + fy;

    // trunc toward zero (matches astype(int32)), then +1, then clip (reference order)
    int x0 = (int)x;
    int x1 = x0 + 1;
    int y0 = (int)y;
    int y1 = y0 + 1;
    x0 = min(max(x0, 0), WN - 1);
    x1 = min(max(x1, 0), WN - 1);
    y0 = min(max(y0, 0), HN - 1);
    y1 = min(max(y1, 0), HN - 1);

    const float x0f = (float)x0, x1f = (float)x1;
    const float y0f = (float)y0, y1f = (float)y1;
    const float wa = (x1f - x) * (y1f - y);
    const float wb = (x1f - x) * (y - y0f);
    const float wc = (x - x0f) * (y1f - y);
    const float wd = (x - x0f) * (y - y0f);

    const int offA = y0 * WN + x0;
    const int offB = y1 * WN + x0;
    const int offC = y0 * WN + x1;
    const int offD = y1 * WN + x1;

    const float* imgb = img + (size_t)b * CN * HW;
    float* outb = out + (size_t)b * CN * HW + hw;

#pragma unroll 4
    for (int c = 0; c < CN; ++c) {
        const float* p = imgb + (size_t)c * HW;
        float Ia = p[offA];
        float Ib = p[offB];
        float Ic = p[offC];
        float Id = p[offD];
        outb[(size_t)c * HW] = wa * Ia + wb * Ib + wc * Ic + wd * Id;
    }
}

extern "C" void kernel_launch(void* const* d_in, const int* in_sizes, int n_in,
                              void* d_out, int out_size, void* d_ws, size_t ws_size,
                              hipStream_t stream) {
    const float* img = (const float*)d_in[0];
    const float* flo = (const float*)d_in[1];
    float* out = (float*)d_out;

    const int total = BN * HW;           // threads = pixels = 917504
    const int block = 256;
    const int grid = (total + block - 1) / block;  // 3584
    warp_kernel<<<grid, block, 0, stream>>>(img, flo, out);
}

// Round 2
// 247.765 us; speedup vs baseline: 1.0261x; 1.0261x over previous
//
#include <hip/hip_runtime.h>

// Bilinear backward warp: img [B,C,H,W] f32, flo [B,2,H,W] f32 -> out [B,C,H,W] f32
// B=8, C=64, H=256, W=448

#define BN 8
#define CN 64
#define HN 256
#define WN 448
#define HW (HN * WN)
#define NXCD 8

__global__ __launch_bounds__(256) void warp_kernel(const float* __restrict__ img,
                                                   const float* __restrict__ flo,
                                                   float* __restrict__ out) {
    // XCD-aware swizzle: grid = 3584 blocks = 448/XCD = exactly one batch image
    // per XCD. Adjacent row-bands then share one XCD's L2 -> img fetched ~once.
    const int nwg = gridDim.x;              // 3584, divisible by 8
    const int cpx = nwg / NXCD;             // 448
    const int bid = blockIdx.x;
    const int wgid = (bid % NXCD) * cpx + (bid / NXCD);

    int pix = wgid * blockDim.x + threadIdx.x;  // over B*H*W
    if (pix >= BN * HW) return;
    int b = pix / HW;
    int hw = pix - b * HW;
    int h = hw / WN;
    int w = hw - h * WN;

    // flow: [B, 2, H, W]
    const float fx = flo[(size_t)b * 2 * HW + hw];
    const float fy = flo[(size_t)b * 2 * HW + HW + hw];
    const float x = (float)w + fx;
    const float y = (float)h + fy;

    // trunc toward zero (matches astype(int32)), then +1, then clip (reference order)
    int x0 = (int)x;
    int x1 = x0 + 1;
    int y0 = (int)y;
    int y1 = y0 + 1;
    x0 = min(max(x0, 0), WN - 1);
    x1 = min(max(x1, 0), WN - 1);
    y0 = min(max(y0, 0), HN - 1);
    y1 = min(max(y1, 0), HN - 1);

    const float x0f = (float)x0, x1f = (float)x1;
    const float y0f = (float)y0, y1f = (float)y1;
    const float wa = (x1f - x) * (y1f - y);
    const float wb = (x1f - x) * (y - y0f);
    const float wc = (x - x0f) * (y1f - y);
    const float wd = (x - x0f) * (y - y0f);

    const int offA = y0 * WN + x0;
    const int offB = y1 * WN + x0;
    const int offC = y0 * WN + x1;
    const int offD = y1 * WN + x1;

    const float* imgb = img + (size_t)b * CN * HW;
    float* outb = out + (size_t)b * CN * HW + hw;

#pragma unroll 8
    for (int c = 0; c < CN; ++c) {
        const float* p = imgb + (size_t)c * HW;
        float Ia = p[offA];
        float Ib = p[offB];
        float Ic = p[offC];
        float Id = p[offD];
        outb[(size_t)c * HW] = wa * Ia + wb * Ib + wc * Ic + wd * Id;
    }
}

extern "C" void kernel_launch(void* const* d_in, const int* in_sizes, int n_in,
                              void* d_out, int out_size, void* d_ws, size_t ws_size,
                              hipStream_t stream) {
    const float* img = (const float*)d_in[0];
    const float* flo = (const float*)d_in[1];
    float* out = (float*)d_out;

    const int total = BN * HW;           // 917504 pixels
    const int block = 256;
    const int grid = (total + block - 1) / block;  // 3584
    warp_kernel<<<grid, block, 0, stream>>>(img, flo, out);
}

// Round 3
// 127.850 us; speedup vs baseline: 1.9884x; 1.9379x over previous
//
#include <hip/hip_runtime.h>

// Bilinear backward warp: img [B,C,H,W] f32, flo [B,2,H,W] f32 -> out [B,C,H,W] f32
// B=8, C=64, H=256, W=448
//
// Strategy: scattered 4-tap gather was vector-L1 line-serialization bound.
// Stage a 10-row band of the current channel plane in LDS (global_load_lds,
// double-buffered), gather from LDS instead. One barrier per channel.

#define BN 8
#define CN 64
#define HN 256
#define WN 448
#define HW (HN * WN)
#define R 4              // output rows per block
#define BAND 10          // staged img rows per channel
#define TPB WN           // 448 threads = 7 waves, one per w column
#define NXCD 8

typedef __attribute__((address_space(1))) const void glb_v;
typedef __attribute__((address_space(3))) void lds_v;

__global__ __launch_bounds__(TPB) void warp_kernel(const float* __restrict__ img,
                                                   const float* __restrict__ flo,
                                                   float* __restrict__ out) {
    // +4 pad: buf[o+1] may read one past the 4480-float band at the very corner
    __shared__ float lds[2][BAND * WN + 4];

    // XCD swizzle: grid = 512 = 8 chunks of 64; chunk k = batch k on XCD k.
    const int nwg = gridDim.x;          // 512
    const int cpx = nwg / NXCD;         // 64
    const int bid = blockIdx.x;
    const int wgid = (bid % NXCD) * cpx + (bid / NXCD);

    const int b    = wgid / (HN / R);   // 0..7
    const int tile = wgid % (HN / R);   // 0..63
    const int h0   = tile * R;
    const int w    = threadIdx.x;       // 0..447

    int lo = h0 - 3;
    lo = lo < 0 ? 0 : (lo > HN - BAND ? HN - BAND : lo);

    const float* imgb = img + (size_t)b * CN * HW;
    const float* flob = flo + (size_t)b * 2 * HW;

    // ---- per-pixel setup (weights + offsets), once for all 64 channels ----
    float wa[R], wb[R], wc[R], wd[R];
    int oA[R], oB[R];   // LDS offsets if in-band, else global (plane-relative)
    int dx_[R];
    bool fb[R];
#pragma unroll
    for (int r = 0; r < R; ++r) {
        const int h = h0 + r;
        const int hw = h * WN + w;
        const float fx = flob[hw];
        const float fy = flob[HW + hw];
        const float x = (float)w + fx;
        const float y = (float)h + fy;
        int x0 = (int)x;                 // trunc toward zero (matches ref)
        int x1 = x0 + 1;
        int y0 = (int)y;
        int y1 = y0 + 1;
        x0 = min(max(x0, 0), WN - 1);
        x1 = min(max(x1, 0), WN - 1);
        y0 = min(max(y0, 0), HN - 1);
        y1 = min(max(y1, 0), HN - 1);
        const float x0f = (float)x0, x1f = (float)x1;
        const float y0f = (float)y0, y1f = (float)y1;
        wa[r] = (x1f - x) * (y1f - y);
        wb[r] = (x1f - x) * (y - y0f);
        wc[r] = (x - x0f) * (y1f - y);
        wd[r] = (x - x0f) * (y - y0f);
        dx_[r] = x1 - x0;                // 0 only at right-edge clip
        const bool inband = (y0 >= lo) && (y1 <= lo + BAND - 1);
        fb[r] = !inband;
        if (inband) {
            oA[r] = (y0 - lo) * WN + x0;
            oB[r] = (y1 - lo) * WN + x0;
        } else {                          // rare (|fy| > ~3)
            oA[r] = y0 * WN + x0;
            oB[r] = y1 * WN + x0;
        }
    }

    const int wave = threadIdx.x >> 6;   // 0..6
    const int lane = threadIdx.x & 63;

    // ---- staging: 10 contiguous rows = 4480 floats = 17x1KB + 2x256B ----
    auto stage = [&](int bufi, int c) {
        const float* src = imgb + (size_t)c * HW + (size_t)lo * WN;
        float* dst = &lds[bufi][0];
        for (int s = wave; s < 17; s += 7) {
            __builtin_amdgcn_global_load_lds(
                (glb_v*)(src + s * 256 + lane * 4),
                (lds_v*)(dst + s * 256), 16, 0, 0);
        }
        if (wave < 2) {
            const int base = 17 * 256 + wave * 64;
            __builtin_amdgcn_global_load_lds(
                (glb_v*)(src + base + lane),
                (lds_v*)(dst + base), 4, 0, 0);
        }
    };

    stage(0, 0);
    __syncthreads();   // drains vmcnt before barrier (compiler-emitted)

    float* outp = out + (size_t)b * CN * HW + (size_t)h0 * WN + w;

    for (int c = 0; c < CN; ++c) {
        const int cur = c & 1;
        if (c + 1 < CN) stage(cur ^ 1, c + 1);

        const float* buf = lds[cur];
        const float* pg = imgb + (size_t)c * HW;   // fallback base
#pragma unroll
        for (int r = 0; r < R; ++r) {
            float Ia, Ib, Ic, Id;
            if (!fb[r]) {
                const float a0 = buf[oA[r]];
                const float a1 = buf[oA[r] + 1];   // fuses to ds_read2_b32
                const float b0 = buf[oB[r]];
                const float b1 = buf[oB[r] + 1];
                Ia = a0; Ic = dx_[r] ? a1 : a0;
                Ib = b0; Id = dx_[r] ? b1 : b0;
            } else {
                Ia = pg[oA[r]];
                Ic = pg[oA[r] + dx_[r]];
                Ib = pg[oB[r]];
                Id = pg[oB[r] + dx_[r]];
            }
            outp[(size_t)c * HW + r * WN] = wa[r] * Ia + wb[r] * Ib + wc[r] * Ic + wd[r] * Id;
        }
        __syncthreads();  // staging(c+1) landed; everyone done reading cur
    }
}

extern "C" void kernel_launch(void* const* d_in, const int* in_sizes, int n_in,
                              void* d_out, int out_size, void* d_ws, size_t ws_size,
                              hipStream_t stream) {
    const float* img = (const float*)d_in[0];
    const float* flo = (const float*)d_in[1];
    float* out = (float*)d_out;

    const int grid = BN * (HN / R);   // 8 * 64 = 512 blocks
    warp_kernel<<<grid, TPB, 0, stream>>>(img, flo, out);
}